// Round 9
// baseline (1729.918 us; speedup 1.0000x reference)
//
#include <hip/hip_runtime.h>

// numpy-fp32 semantics: explicit fmaf only, no implicit contraction.
#pragma clang fp contract(off)

typedef unsigned char u8;
typedef unsigned int u32;

#define TSTEPS 4

// ---------------------------------------------------------------------------
// FUSED conv+BN+LIF (R7 structure: grid-expanded NSEL, single barrier,
// C-cast u8->f32 [hipcc folds to v_cvt_f32_ubyteN], R8 generalized loader).
// Used on the fallback path (small workspace).
// ---------------------------------------------------------------------------
template <int P, int BK, int XMODE, bool HASX2, int OMODE, int NSEL>
__global__ __launch_bounds__(256) void conv_bn_lif(
    const void* __restrict__ X1v, const u8* __restrict__ X2,
    const float* __restrict__ W0, const float* __restrict__ W1,
    const float* __restrict__ W2, const float* __restrict__ bias,
    const float* __restrict__ bn0, const float* __restrict__ bn1,
    const float* __restrict__ bn2,
    u8* __restrict__ S0, u8* __restrict__ S1, u8* __restrict__ S2,
    const float* __restrict__ Xres, const u8* __restrict__ AOres,
    float* __restrict__ Fout,
    int Bsz, int Cin, int Cout, int N)
{
  constexpr int BO   = 16 * P;
  constexpr int BN   = 128;
  constexpr int TPRX = 256 / BK;
  constexpr int XPT  = BN / TPRX;
  constexpr int NXC  = (XMODE == 0) ? XPT / 4 : XPT / 16;
  static_assert(XMODE == 1 || (BK == 32 && NXC == 4), "f32 X needs BK=32");
  constexpr int WPT  = BO * BK / 256;
  constexpr int NW4  = WPT / 4;
  constexpr int TPW  = BK / WPT;
  constexpr int WPAD = (P == 4) ? 4 : (P == 2) ? 2 : 0;
  constexpr int WROW = BO + WPAD;
  constexpr int XROWF = BN + 8;

  const int tid = threadIdx.x;
  const int tx = tid & 15, ty = tid >> 4;
  const int nBase = blockIdx.x * BN, b = blockIdx.z;

  int sel, oBase;
  if constexpr (NSEL == 3) {
    const int oT = gridDim.y / 3;
    sel = blockIdx.y / oT;
    oBase = (blockIdx.y - sel * oT) * BO;
  } else {
    sel = 0;
    oBase = blockIdx.y * BO;
  }
  const float* __restrict__ Wt  = (sel == 0) ? W0 : (sel == 1) ? W1 : W2;
  const float* __restrict__ bnp = (sel == 0) ? bn0 : (sel == 1) ? bn1 : bn2;
  u8* __restrict__ Sout         = (sel == 0) ? S0 : (sel == 1) ? S1 : S2;

  const int KT = Cin / BK;
  const int TT = TSTEPS * KT;

  __shared__ __align__(16) float Ws[2][BK][WROW];
  __shared__ __align__(16) u8 Xraw[(XMODE == 0) ? (2 * BK * XROWF * 4)
                                                : (2 * BK * BN)];
  __shared__ __align__(16) float BnL[BO][4];  // sc, mn, bt, bi

  float* XF = (float*)Xraw;
  u8*    X8 = Xraw;

  if (tid < BO) {
    int o = oBase + tid;
    float g  = bnp[0 * Cout + o];
    float be = bnp[1 * Cout + o];
    float m  = bnp[2 * Cout + o];
    float vv = bnp[3 * Cout + o];
    float d_f = (float)((double)vv + (double)1e-5f);
    float s_f = (float)sqrt((double)d_f);
    BnL[tid][0] = (float)((double)g / (double)s_f);
    BnL[tid][1] = m;
    BnL[tid][2] = be;
    BnL[tid][3] = bias ? bias[o] : 0.0f;
  }

  float mem[P][8], acc[P][8];
  #pragma unroll
  for (int p = 0; p < P; ++p)
    #pragma unroll
    for (int q = 0; q < 8; ++q) { mem[p][q] = 0.0f; acc[p][q] = 0.0f; }

  const int xRow = tid / TPRX;
  const int xOff = (tid % TPRX) * XPT;
  const int wO   = tid / TPW;
  const int wK   = (tid % TPW) * WPT;

  float4 px[(XMODE == 0) ? NXC : 1];
  uint4  pxu[(XMODE == 1) ? NXC : 1];
  u32    pau[4];
  float4 pw[NW4];

  auto issue = [&](int i) {
    const int tI = i / KT, k0 = (i % KT) * BK;
    const size_t xb = (size_t)(tI * Bsz + b) * Cin * N
                    + (size_t)(k0 + xRow) * N + nBase + xOff;
    if constexpr (XMODE == 0) {
      const float* xp = (const float*)X1v + xb;
      #pragma unroll
      for (int f = 0; f < NXC; ++f) px[f] = *(const float4*)(xp + 4 * f);
    } else {
      const u8* xp = (const u8*)X1v + xb;
      #pragma unroll
      for (int f = 0; f < NXC; ++f) pxu[f] = *(const uint4*)(xp + 16 * f);
    }
    if constexpr (HASX2) {
      uint4 u = *(const uint4*)(X2 + xb);
      pau[0] = u.x; pau[1] = u.y; pau[2] = u.z; pau[3] = u.w;
    }
    const size_t wb = (size_t)(oBase + wO) * Cin + k0 + wK;
    #pragma unroll
    for (int f = 0; f < NW4; ++f) pw[f] = *(const float4*)(Wt + wb + 4 * f);
  };

  auto commit = [&](int bf) {
    if constexpr (XMODE == 0) {
      #pragma unroll
      for (int f = 0; f < NXC; ++f) {
        float4 v = px[f];
        if constexpr (HASX2) {
          u32 a2 = pau[f];
          v.x = v.x + (float)(a2 & 0xffu);
          v.y = v.y + (float)((a2 >> 8) & 0xffu);
          v.z = v.z + (float)((a2 >> 16) & 0xffu);
          v.w = v.w + (float)((a2 >> 24) & 0xffu);
        }
        *(float4*)&XF[((size_t)(bf * BK + xRow)) * XROWF + xOff + 4 * f] = v;
      }
    } else {
      #pragma unroll
      for (int f = 0; f < NXC; ++f)
        *(uint4*)&X8[(size_t)(bf * BK + xRow) * BN + xOff + 16 * f] = pxu[f];
    }
    #pragma unroll
    for (int f = 0; f < NW4; ++f) {
      Ws[bf][wK + 4 * f + 0][wO] = pw[f].x;
      Ws[bf][wK + 4 * f + 1][wO] = pw[f].y;
      Ws[bf][wK + 4 * f + 2][wO] = pw[f].z;
      Ws[bf][wK + 4 * f + 3][wO] = pw[f].w;
    }
  };

  issue(0);
  commit(0);
  __syncthreads();

  for (int tt = 0; tt < TT; ++tt) {
    const int buf = tt & 1;
    if (tt + 1 < TT) issue(tt + 1);

    #pragma unroll
    for (int kk = 0; kk < BK; ++kk) {   // ascending k, bit-exact FMA chain
      float xa[8];
      if constexpr (XMODE == 0) {
        float4 x0 = *(const float4*)&XF[(size_t)(buf * BK + kk) * XROWF + tx * 4];
        float4 x1 = *(const float4*)&XF[(size_t)(buf * BK + kk) * XROWF + 64 + tx * 4];
        xa[0] = x0.x; xa[1] = x0.y; xa[2] = x0.z; xa[3] = x0.w;
        xa[4] = x1.x; xa[5] = x1.y; xa[6] = x1.z; xa[7] = x1.w;
      } else {
        uint2 u = *(const uint2*)&X8[(size_t)(buf * BK + kk) * BN + tx * 8];
        #pragma unroll
        for (int j = 0; j < 4; ++j) xa[j]     = (float)((u.x >> (8 * j)) & 0xffu);
        #pragma unroll
        for (int j = 0; j < 4; ++j) xa[4 + j] = (float)((u.y >> (8 * j)) & 0xffu);
      }
      float wa[P];
      if constexpr (P == 2) {
        float2 w0 = *(const float2*)&Ws[buf][kk][ty * 2];
        wa[0] = w0.x; wa[1] = w0.y;
      } else {
        float4 w0 = *(const float4*)&Ws[buf][kk][ty * P];
        wa[0] = w0.x; wa[1] = w0.y; wa[2] = w0.z; wa[3] = w0.w;
        if constexpr (P == 8) {
          float4 w1 = *(const float4*)&Ws[buf][kk][ty * P + 4];
          wa[4] = w1.x; wa[5] = w1.y; wa[6] = w1.z; wa[7] = w1.w;
        }
      }
      #pragma unroll
      for (int p = 0; p < P; ++p)
        #pragma unroll
        for (int q = 0; q < 8; ++q)
          acc[p][q] = fmaf(wa[p], xa[q], acc[p][q]);
    }

    if ((tt % KT) == KT - 1) {
      const int t = tt / KT;
      const size_t sbase = (size_t)(t * Bsz + b) * Cout * N;
      #pragma unroll
      for (int p = 0; p < P; ++p) {
        const int o = oBase + ty * P + p;
        float4 bv = *(const float4*)&BnL[ty * P + p][0];
        bool spk[8];
        #pragma unroll
        for (int q = 0; q < 8; ++q) {
          float y = acc[p][q];
          if (bias) y = y + bv.w;
          float t1 = y - bv.y;
          float t2 = t1 * bv.x;
          y = t2 + bv.z;
          float m2 = mem[p][q];
          float dd = y - m2;
          m2 = m2 + dd * 0.5f;
          bool sp = (m2 - 0.5f) > 0.0f;
          mem[p][q] = sp ? 0.0f : m2;
          spk[q] = sp;
          acc[p][q] = 0.0f;
        }
        if constexpr (XMODE == 0) {
          const size_t rb0 = sbase + (size_t)o * N + nBase + tx * 4;
          u32 pk0 = 0, pk1 = 0;
          #pragma unroll
          for (int j = 0; j < 4; ++j) {
            if (spk[j])     pk0 |= (1u << (8 * j));
            if (spk[4 + j]) pk1 |= (1u << (8 * j));
          }
          *(u32*)&Sout[rb0]      = pk0;
          *(u32*)&Sout[rb0 + 64] = pk1;
        } else {
          const size_t rb = sbase + (size_t)o * N + nBase + tx * 8;
          if constexpr (OMODE == 0) {
            u32 pk0 = 0, pk1 = 0;
            #pragma unroll
            for (int j = 0; j < 4; ++j) {
              if (spk[j])     pk0 |= (1u << (8 * j));
              if (spk[4 + j]) pk1 |= (1u << (8 * j));
            }
            *(uint2*)&Sout[rb] = make_uint2(pk0, pk1);
          } else {
            float4 xr0 = *(const float4*)&Xres[rb];
            float4 xr1 = *(const float4*)&Xres[rb + 4];
            uint2 av = *(const uint2*)&AOres[rb];
            float xa4[8] = {xr0.x, xr0.y, xr0.z, xr0.w,
                            xr1.x, xr1.y, xr1.z, xr1.w};
            float o4[8];
            #pragma unroll
            for (int j = 0; j < 4; ++j) {
              float sv = spk[j] ? 1.0f : 0.0f;
              float xn = xa4[j] + (float)((av.x >> (8 * j)) & 0xffu);
              o4[j] = xn + sv;
            }
            #pragma unroll
            for (int j = 0; j < 4; ++j) {
              float sv = spk[4 + j] ? 1.0f : 0.0f;
              float xn = xa4[4 + j] + (float)((av.y >> (8 * j)) & 0xffu);
              o4[4 + j] = xn + sv;
            }
            *(float4*)&Fout[rb]     = make_float4(o4[0], o4[1], o4[2], o4[3]);
            *(float4*)&Fout[rb + 4] = make_float4(o4[4], o4[5], o4[6], o4[7]);
          }
        }
      }
    }

    if (tt + 1 < TT) commit((tt + 1) & 1);
    __syncthreads();
  }
}

// ---------------------------------------------------------------------------
// SPLIT PATH kernel 1: conv+BN only, t-PARALLEL (blockIdx.z = t*Bsz + b),
// f32 y output.  Grid is T x larger -> 4-8 blocks/CU, no mem[] recurrence,
// no in-loop epilogue.  Bit-exact: same ascending-k fmaf chain + BN exprs.
// ---------------------------------------------------------------------------
template <int P, int BK, int XMODE, bool HASX2, int NSEL>
__global__ __launch_bounds__(256) void conv_bn_t(
    const void* __restrict__ X1v, const u8* __restrict__ X2,
    const float* __restrict__ W0, const float* __restrict__ W1,
    const float* __restrict__ W2, const float* __restrict__ bias,
    const float* __restrict__ bn0, const float* __restrict__ bn1,
    const float* __restrict__ bn2,
    float* __restrict__ Y0, float* __restrict__ Y1, float* __restrict__ Y2,
    int Bsz, int Cin, int Cout, int N)
{
  constexpr int BO   = 16 * P;
  constexpr int BN   = 128;
  constexpr int TPRX = 256 / BK;
  constexpr int XPT  = BN / TPRX;
  constexpr int NXC  = (XMODE == 0) ? XPT / 4 : XPT / 16;
  static_assert(XMODE == 1 || (BK == 32 && NXC == 4), "f32 X needs BK=32");
  constexpr int WPT  = BO * BK / 256;
  constexpr int NW4  = WPT / 4;
  constexpr int TPW  = BK / WPT;
  constexpr int WPAD = (P == 4) ? 4 : (P == 2) ? 2 : 0;
  constexpr int WROW = BO + WPAD;
  constexpr int XROWF = BN + 8;

  const int tid = threadIdx.x;
  const int tx = tid & 15, ty = tid >> 4;
  const int nBase = blockIdx.x * BN;
  const int zb = blockIdx.z;
  const int tI = zb / Bsz, b = zb % Bsz;

  int sel, oBase;
  if constexpr (NSEL == 3) {
    const int oT = gridDim.y / 3;
    sel = blockIdx.y / oT;
    oBase = (blockIdx.y - sel * oT) * BO;
  } else {
    sel = 0;
    oBase = blockIdx.y * BO;
  }
  const float* __restrict__ Wt  = (sel == 0) ? W0 : (sel == 1) ? W1 : W2;
  const float* __restrict__ bnp = (sel == 0) ? bn0 : (sel == 1) ? bn1 : bn2;
  float* __restrict__ Yout      = (sel == 0) ? Y0 : (sel == 1) ? Y1 : Y2;

  const int KT = Cin / BK;

  __shared__ __align__(16) float Ws[2][BK][WROW];
  __shared__ __align__(16) u8 Xraw[(XMODE == 0) ? (2 * BK * XROWF * 4)
                                                : (2 * BK * BN)];
  __shared__ __align__(16) float BnL[BO][4];

  float* XF = (float*)Xraw;
  u8*    X8 = Xraw;

  if (tid < BO) {
    int o = oBase + tid;
    float g  = bnp[0 * Cout + o];
    float be = bnp[1 * Cout + o];
    float m  = bnp[2 * Cout + o];
    float vv = bnp[3 * Cout + o];
    float d_f = (float)((double)vv + (double)1e-5f);
    float s_f = (float)sqrt((double)d_f);
    BnL[tid][0] = (float)((double)g / (double)s_f);
    BnL[tid][1] = m;
    BnL[tid][2] = be;
    BnL[tid][3] = bias ? bias[o] : 0.0f;
  }

  float acc[P][8];
  #pragma unroll
  for (int p = 0; p < P; ++p)
    #pragma unroll
    for (int q = 0; q < 8; ++q) acc[p][q] = 0.0f;

  const int xRow = tid / TPRX;
  const int xOff = (tid % TPRX) * XPT;
  const int wO   = tid / TPW;
  const int wK   = (tid % TPW) * WPT;

  float4 px[(XMODE == 0) ? NXC : 1];
  uint4  pxu[(XMODE == 1) ? NXC : 1];
  u32    pau[4];
  float4 pw[NW4];

  auto issue = [&](int i) {
    const int k0 = i * BK;
    const size_t xb = (size_t)(tI * Bsz + b) * Cin * N
                    + (size_t)(k0 + xRow) * N + nBase + xOff;
    if constexpr (XMODE == 0) {
      const float* xp = (const float*)X1v + xb;
      #pragma unroll
      for (int f = 0; f < NXC; ++f) px[f] = *(const float4*)(xp + 4 * f);
    } else {
      const u8* xp = (const u8*)X1v + xb;
      #pragma unroll
      for (int f = 0; f < NXC; ++f) pxu[f] = *(const uint4*)(xp + 16 * f);
    }
    if constexpr (HASX2) {
      uint4 u = *(const uint4*)(X2 + xb);
      pau[0] = u.x; pau[1] = u.y; pau[2] = u.z; pau[3] = u.w;
    }
    const size_t wb = (size_t)(oBase + wO) * Cin + k0 + wK;
    #pragma unroll
    for (int f = 0; f < NW4; ++f) pw[f] = *(const float4*)(Wt + wb + 4 * f);
  };

  auto commit = [&](int bf) {
    if constexpr (XMODE == 0) {
      #pragma unroll
      for (int f = 0; f < NXC; ++f) {
        float4 v = px[f];
        if constexpr (HASX2) {
          u32 a2 = pau[f];
          v.x = v.x + (float)(a2 & 0xffu);
          v.y = v.y + (float)((a2 >> 8) & 0xffu);
          v.z = v.z + (float)((a2 >> 16) & 0xffu);
          v.w = v.w + (float)((a2 >> 24) & 0xffu);
        }
        *(float4*)&XF[((size_t)(bf * BK + xRow)) * XROWF + xOff + 4 * f] = v;
      }
    } else {
      #pragma unroll
      for (int f = 0; f < NXC; ++f)
        *(uint4*)&X8[(size_t)(bf * BK + xRow) * BN + xOff + 16 * f] = pxu[f];
    }
    #pragma unroll
    for (int f = 0; f < NW4; ++f) {
      Ws[bf][wK + 4 * f + 0][wO] = pw[f].x;
      Ws[bf][wK + 4 * f + 1][wO] = pw[f].y;
      Ws[bf][wK + 4 * f + 2][wO] = pw[f].z;
      Ws[bf][wK + 4 * f + 3][wO] = pw[f].w;
    }
  };

  issue(0);
  commit(0);
  __syncthreads();

  for (int tt = 0; tt < KT; ++tt) {
    const int buf = tt & 1;
    if (tt + 1 < KT) issue(tt + 1);

    #pragma unroll
    for (int kk = 0; kk < BK; ++kk) {   // ascending k, bit-exact FMA chain
      float xa[8];
      if constexpr (XMODE == 0) {
        float4 x0 = *(const float4*)&XF[(size_t)(buf * BK + kk) * XROWF + tx * 4];
        float4 x1 = *(const float4*)&XF[(size_t)(buf * BK + kk) * XROWF + 64 + tx * 4];
        xa[0] = x0.x; xa[1] = x0.y; xa[2] = x0.z; xa[3] = x0.w;
        xa[4] = x1.x; xa[5] = x1.y; xa[6] = x1.z; xa[7] = x1.w;
      } else {
        uint2 u = *(const uint2*)&X8[(size_t)(buf * BK + kk) * BN + tx * 8];
        #pragma unroll
        for (int j = 0; j < 4; ++j) xa[j]     = (float)((u.x >> (8 * j)) & 0xffu);
        #pragma unroll
        for (int j = 0; j < 4; ++j) xa[4 + j] = (float)((u.y >> (8 * j)) & 0xffu);
      }
      float wa[P];
      if constexpr (P == 2) {
        float2 w0 = *(const float2*)&Ws[buf][kk][ty * 2];
        wa[0] = w0.x; wa[1] = w0.y;
      } else {
        float4 w0 = *(const float4*)&Ws[buf][kk][ty * P];
        wa[0] = w0.x; wa[1] = w0.y; wa[2] = w0.z; wa[3] = w0.w;
        if constexpr (P == 8) {
          float4 w1 = *(const float4*)&Ws[buf][kk][ty * P + 4];
          wa[4] = w1.x; wa[5] = w1.y; wa[6] = w1.z; wa[7] = w1.w;
        }
      }
      #pragma unroll
      for (int p = 0; p < P; ++p)
        #pragma unroll
        for (int q = 0; q < 8; ++q)
          acc[p][q] = fmaf(wa[p], xa[q], acc[p][q]);
    }

    if (tt + 1 < KT) {
      commit((tt + 1) & 1);
      __syncthreads();
    }
  }

  // epilogue: BN (identical exprs), f32 store
  const size_t sbase = (size_t)(tI * Bsz + b) * Cout * N;
  #pragma unroll
  for (int p = 0; p < P; ++p) {
    const int o = oBase + ty * P + p;
    float4 bv = *(const float4*)&BnL[ty * P + p][0];
    float o4[8];
    #pragma unroll
    for (int q = 0; q < 8; ++q) {
      float y = acc[p][q];
      if (bias) y = y + bv.w;
      float t1 = y - bv.y;
      float t2 = t1 * bv.x;
      o4[q] = t2 + bv.z;
    }
    if constexpr (XMODE == 0) {
      const size_t rb0 = sbase + (size_t)o * N + nBase + tx * 4;
      *(float4*)&Yout[rb0]      = make_float4(o4[0], o4[1], o4[2], o4[3]);
      *(float4*)&Yout[rb0 + 64] = make_float4(o4[4], o4[5], o4[6], o4[7]);
    } else {
      const size_t rb = sbase + (size_t)o * N + nBase + tx * 8;
      *(float4*)&Yout[rb]     = make_float4(o4[0], o4[1], o4[2], o4[3]);
      *(float4*)&Yout[rb + 4] = make_float4(o4[4], o4[5], o4[6], o4[7]);
    }
  }
}

// ---------------------------------------------------------------------------
// SPLIT PATH kernel 2: LIF scan over t (memory-bound elementwise).
// FMODE 0: u8 spikes out.  FMODE 1: final out = (x + ao) + spike.
// Expressions identical to the fused epilogue -> bit-exact.
// ---------------------------------------------------------------------------
template <int NSEL, int FMODE>
__global__ __launch_bounds__(256) void lif_scan(
    const float* __restrict__ Y0, const float* __restrict__ Y1,
    const float* __restrict__ Y2,
    u8* __restrict__ S0, u8* __restrict__ S1, u8* __restrict__ S2,
    const float* __restrict__ Xres, const u8* __restrict__ AOres,
    float* __restrict__ Fout, int Bsz, int cnShift)
{
  const size_t off = ((size_t)blockIdx.x * 256 + threadIdx.x) * 4;
  const size_t stride = (size_t)Bsz << cnShift;
  const float* Ya[3] = {Y0, Y1, Y2};
  u8* Sa[3] = {S0, S1, S2};

  float mem[NSEL][4];
  #pragma unroll
  for (int s = 0; s < NSEL; ++s)
    #pragma unroll
    for (int j = 0; j < 4; ++j) mem[s][j] = 0.0f;

  for (int t = 0; t < TSTEPS; ++t) {
    const size_t pos = off + (size_t)t * stride;
    #pragma unroll
    for (int s = 0; s < NSEL; ++s) {
      float4 yv = *(const float4*)(Ya[s] + pos);
      float ya[4] = {yv.x, yv.y, yv.z, yv.w};
      bool spk[4];
      #pragma unroll
      for (int j = 0; j < 4; ++j) {
        float m2 = mem[s][j];
        float dd = ya[j] - m2;
        m2 = m2 + dd * 0.5f;
        bool sp = (m2 - 0.5f) > 0.0f;
        mem[s][j] = sp ? 0.0f : m2;
        spk[j] = sp;
      }
      if constexpr (FMODE == 0) {
        u32 pack = 0;
        #pragma unroll
        for (int j = 0; j < 4; ++j)
          if (spk[j]) pack |= (1u << (8 * j));
        *(u32*)&Sa[s][pos] = pack;
      } else {
        float4 xr = *(const float4*)(Xres + pos);
        u32 av = *(const u32*)(AOres + pos);
        float xa4[4] = {xr.x, xr.y, xr.z, xr.w};
        float o4[4];
        #pragma unroll
        for (int j = 0; j < 4; ++j) {
          float sv = spk[j] ? 1.0f : 0.0f;
          float xn = xa4[j] + (float)((av >> (8 * j)) & 0xffu);
          o4[j] = xn + sv;
        }
        *(float4*)&Fout[pos] = make_float4(o4[0], o4[1], o4[2], o4[3]);
      }
    }
  }
}

// Attention + attn-LIF, q @ (k^T v): integer-exact (unchanged, verified).
__global__ __launch_bounds__(256) void attn_lif(
    const u8* __restrict__ Qs, const u8* __restrict__ Ks,
    const u8* __restrict__ Vs, u8* __restrict__ Rs,
    int Bsz, int C, int N)
{
  const int tid = threadIdx.x;
  const int h = blockIdx.x & 15;
  const int b = blockIdx.x >> 4;

  __shared__ u8 qs[16][528];
  __shared__ u8 ks[16][528];
  __shared__ u8 vs[16][528];
  __shared__ int Gs[16][17];

  const int eG = tid >> 4;
  const int dG = tid & 15;
  const int dR = tid >> 4;
  const int nR0 = tid & 15;

  float mem[32];
  #pragma unroll
  for (int i = 0; i < 32; ++i) mem[i] = 0.0f;

  for (int t = 0; t < TSTEPS; ++t) {
    __syncthreads();
    const size_t base = ((size_t)(t * Bsz + b) * C + h * 16) * N;
    for (int i = 0; i < 32; ++i) {
      int flat = tid + 256 * i;
      int d = flat >> 9, n = flat & 511;
      size_t g = base + (size_t)d * N + n;
      qs[d][n] = Qs[g];
      ks[d][n] = Ks[g];
      vs[d][n] = Vs[g];
    }
    __syncthreads();

    int gi = 0;
    for (int n = 0; n < 512; ++n)
      gi += (int)ks[eG][n] * (int)vs[dG][n];
    Gs[eG][dG] = gi;
    __syncthreads();

    int Greg[16];
    #pragma unroll
    for (int e = 0; e < 16; ++e) Greg[e] = Gs[e][dR];

    const size_t obase = ((size_t)(t * Bsz + b) * C + h * 16 + dR) * N;
    for (int j = 0; j < 32; ++j) {
      int n = nR0 + 16 * j;
      int ri = 0;
      #pragma unroll
      for (int e = 0; e < 16; ++e)
        ri += qs[e][n] ? Greg[e] : 0;
      float r = (float)ri * 0.0625f;
      float m2 = mem[j];
      float d = r - m2;
      m2 = m2 + d * 0.5f;
      float s = (m2 - 0.5f) > 0.0f ? 1.0f : 0.0f;
      mem[j] = (s > 0.0f) ? 0.0f : m2;
      Rs[obase + n] = (s > 0.0f) ? (u8)1 : (u8)0;
    }
  }
}

extern "C" void kernel_launch(void* const* d_in, const int* in_sizes, int n_in,
                              void* d_out, int out_size, void* d_ws, size_t ws_size,
                              hipStream_t stream)
{
  const float* x     = (const float*)d_in[0];
  const float* q_w   = (const float*)d_in[1];
  const float* q_bn  = (const float*)d_in[2];
  const float* k_w   = (const float*)d_in[3];
  const float* k_bn  = (const float*)d_in[4];
  const float* v_w   = (const float*)d_in[5];
  const float* v_bn  = (const float*)d_in[6];
  const float* p_w   = (const float*)d_in[7];
  const float* p_bn  = (const float*)d_in[8];
  const float* f1_w  = (const float*)d_in[9];
  const float* f1_b  = (const float*)d_in[10];
  const float* f1_bn = (const float*)d_in[11];
  const float* f2_w  = (const float*)d_in[12];
  const float* f2_b  = (const float*)d_in[13];
  const float* f2_bn = (const float*)d_in[14];

  const int T = 4, B = 16, C = 256, N = 512, Hm = 1024;
  const size_t SZ = (size_t)T * B * C * N;   // u8 spike buffer bytes (8.4 MB)

  char* ws = (char*)d_ws;
  u8* q_s  = (u8*)(ws + 0 * SZ);
  u8* k_s  = (u8*)(ws + 1 * SZ);
  u8* v_s  = (u8*)(ws + 2 * SZ);
  u8* r_s  = (u8*)(ws + 3 * SZ);
  u8* ao_s = (u8*)(ws + 4 * SZ);
  u8* h_s  = (u8*)(ws + 0 * SZ);             // h (4*SZ) overlays dead q/k/v/r

  dim3 blk(256);

  // Split path needs: 5*SZ (u8) + 16*SZ (f32 scratch A, sized for fc1's y).
  const size_t NEED = 21 * SZ;               // 176.2 MB

  if (ws_size >= NEED) {
    // ---------------- SPLIT PATH: t-parallel conv + LIF scans ----------------
    float* yA = (float*)(ws + 5 * SZ);       // 16*SZ bytes of f32 scratch
    float* yq = yA;                          // QKV y: 3 x SZ floats
    float* yk = yA + SZ;
    float* yv = yA + 2 * SZ;
    float* yp = yA;                          // proj y (QKV y dead)
    float* yh = yA;                          // fc1 y: 4*SZ floats (yp dead)
    float* yo = yA;                          // fc2 y (yh dead after h scan)

    dim3 gQKV(N / 128, 3 * (C / 64), T * B);   // (4,12,64) P=4
    dim3 gP(N / 128, C / 32, T * B);           // (4, 8,64) P=2
    dim3 gF1(N / 128, Hm / 128, T * B);        // (4, 8,64) P=8
    const int sC = 17;                         // log2(C*N)
    const int sH = 19;                         // log2(Hm*N)
    dim3 gScanC((B << sC) / 1024);             // 2048
    dim3 gScanH((B << sH) / 1024);             // 8192

    conv_bn_t<4, 32, 0, false, 3><<<gQKV, blk, 0, stream>>>(
        x, nullptr, q_w, k_w, v_w, nullptr, q_bn, k_bn, v_bn,
        yq, yk, yv, B, C, C, N);
    lif_scan<3, 0><<<gScanC, blk, 0, stream>>>(
        yq, yk, yv, q_s, k_s, v_s, nullptr, nullptr, nullptr, B, sC);

    attn_lif<<<dim3(B * 16), blk, 0, stream>>>(q_s, k_s, v_s, r_s, B, C, N);

    conv_bn_t<2, 32, 1, false, 1><<<gP, blk, 0, stream>>>(
        r_s, nullptr, p_w, p_w, p_w, nullptr, p_bn, p_bn, p_bn,
        yp, yp, yp, B, C, C, N);
    lif_scan<1, 0><<<gScanC, blk, 0, stream>>>(
        yp, nullptr, nullptr, ao_s, nullptr, nullptr, nullptr, nullptr,
        nullptr, B, sC);

    conv_bn_t<8, 32, 0, true, 1><<<gF1, blk, 0, stream>>>(
        x, ao_s, f1_w, f1_w, f1_w, f1_b, f1_bn, f1_bn, f1_bn,
        yh, yh, yh, B, C, Hm, N);
    lif_scan<1, 0><<<gScanH, blk, 0, stream>>>(
        yh, nullptr, nullptr, h_s, nullptr, nullptr, nullptr, nullptr,
        nullptr, B, sH);

    conv_bn_t<2, 32, 1, false, 1><<<gP, blk, 0, stream>>>(
        h_s, nullptr, f2_w, f2_w, f2_w, f2_b, f2_bn, f2_bn, f2_bn,
        yo, yo, yo, B, Hm, C, N);
    lif_scan<1, 1><<<gScanC, blk, 0, stream>>>(
        yo, nullptr, nullptr, nullptr, nullptr, nullptr, x, ao_s,
        (float*)d_out, B, sC);
  } else {
    // ---------------- FALLBACK: fused path (R7 structure) -------------------
    dim3 gQKV(N / 128, 3 * (C / 64), B);   // (4,12,16)
    dim3 gP2(N / 128, C / 32, B);          // (4, 8,16)
    dim3 gF1(N / 128, Hm / 128, B);        // (4, 8,16)

    conv_bn_lif<4, 32, 0, false, 0, 3><<<gQKV, blk, 0, stream>>>(
        x, nullptr, q_w, k_w, v_w, nullptr, q_bn, k_bn, v_bn,
        q_s, k_s, v_s, nullptr, nullptr, nullptr, B, C, C, N);

    attn_lif<<<dim3(B * 16), blk, 0, stream>>>(q_s, k_s, v_s, r_s, B, C, N);

    conv_bn_lif<2, 64, 1, false, 0, 1><<<gP2, blk, 0, stream>>>(
        r_s, nullptr, p_w, p_w, p_w, nullptr, p_bn, p_bn, p_bn,
        ao_s, ao_s, ao_s, nullptr, nullptr, nullptr, B, C, C, N);
    conv_bn_lif<8, 32, 0, true, 0, 1><<<gF1, blk, 0, stream>>>(
        x, ao_s, f1_w, f1_w, f1_w, f1_b, f1_bn, f1_bn, f1_bn,
        h_s, h_s, h_s, nullptr, nullptr, nullptr, B, C, Hm, N);
    conv_bn_lif<2, 64, 1, false, 1, 1><<<gP2, blk, 0, stream>>>(
        h_s, nullptr, f2_w, f2_w, f2_w, f2_b, f2_bn, f2_bn, f2_bn,
        nullptr, nullptr, nullptr, x, ao_s, (float*)d_out, B, Hm, C, N);
  }
}

// Round 11
// 1117.093 us; speedup vs baseline: 1.5486x; 1.5486x over previous
//
#include <hip/hip_runtime.h>

// numpy-fp32 semantics: explicit fmaf only, no implicit contraction.
#pragma clang fp contract(off)

typedef unsigned char u8;
typedef unsigned int u32;

#define TSTEPS 4

// ---------------------------------------------------------------------------
// FUSED conv+BN+LIF (R7 structure, measured 979-run): grid-expanded NSEL,
// single barrier per k-tile, C-cast u8->f32.  Used for QKV (+ fallback).
// ---------------------------------------------------------------------------
template <int P, int BK, int XMODE, bool HASX2, int OMODE, int NSEL>
__global__ __launch_bounds__(256) void conv_bn_lif(
    const void* __restrict__ X1v, const u8* __restrict__ X2,
    const float* __restrict__ W0, const float* __restrict__ W1,
    const float* __restrict__ W2, const float* __restrict__ bias,
    const float* __restrict__ bn0, const float* __restrict__ bn1,
    const float* __restrict__ bn2,
    u8* __restrict__ S0, u8* __restrict__ S1, u8* __restrict__ S2,
    const float* __restrict__ Xres, const u8* __restrict__ AOres,
    float* __restrict__ Fout,
    int Bsz, int Cin, int Cout, int N)
{
  constexpr int BO   = 16 * P;
  constexpr int BN   = 128;
  constexpr int TPRX = 256 / BK;
  constexpr int XPT  = BN / TPRX;
  constexpr int NXC  = (XMODE == 0) ? XPT / 4 : XPT / 16;
  static_assert(XMODE == 1 || (BK == 32 && NXC == 4), "f32 X needs BK=32");
  constexpr int WPT  = BO * BK / 256;
  constexpr int NW4  = WPT / 4;
  constexpr int TPW  = BK / WPT;
  constexpr int WPAD = (P == 4) ? 4 : (P == 2) ? 2 : 0;
  constexpr int WROW = BO + WPAD;
  constexpr int XROWF = BN + 8;

  const int tid = threadIdx.x;
  const int tx = tid & 15, ty = tid >> 4;
  const int nBase = blockIdx.x * BN, b = blockIdx.z;

  int sel, oBase;
  if constexpr (NSEL == 3) {
    const int oT = gridDim.y / 3;
    sel = blockIdx.y / oT;
    oBase = (blockIdx.y - sel * oT) * BO;
  } else {
    sel = 0;
    oBase = blockIdx.y * BO;
  }
  const float* __restrict__ Wt  = (sel == 0) ? W0 : (sel == 1) ? W1 : W2;
  const float* __restrict__ bnp = (sel == 0) ? bn0 : (sel == 1) ? bn1 : bn2;
  u8* __restrict__ Sout         = (sel == 0) ? S0 : (sel == 1) ? S1 : S2;

  const int KT = Cin / BK;
  const int TT = TSTEPS * KT;

  __shared__ __align__(16) float Ws[2][BK][WROW];
  __shared__ __align__(16) u8 Xraw[(XMODE == 0) ? (2 * BK * XROWF * 4)
                                                : (2 * BK * BN)];
  __shared__ __align__(16) float BnL[BO][4];  // sc, mn, bt, bi

  float* XF = (float*)Xraw;
  u8*    X8 = Xraw;

  if (tid < BO) {
    int o = oBase + tid;
    float g  = bnp[0 * Cout + o];
    float be = bnp[1 * Cout + o];
    float m  = bnp[2 * Cout + o];
    float vv = bnp[3 * Cout + o];
    float d_f = (float)((double)vv + (double)1e-5f);
    float s_f = (float)sqrt((double)d_f);
    BnL[tid][0] = (float)((double)g / (double)s_f);
    BnL[tid][1] = m;
    BnL[tid][2] = be;
    BnL[tid][3] = bias ? bias[o] : 0.0f;
  }

  float mem[P][8], acc[P][8];
  #pragma unroll
  for (int p = 0; p < P; ++p)
    #pragma unroll
    for (int q = 0; q < 8; ++q) { mem[p][q] = 0.0f; acc[p][q] = 0.0f; }

  const int xRow = tid / TPRX;
  const int xOff = (tid % TPRX) * XPT;
  const int wO   = tid / TPW;
  const int wK   = (tid % TPW) * WPT;

  float4 px[(XMODE == 0) ? NXC : 1];
  uint4  pxu[(XMODE == 1) ? NXC : 1];
  u32    pau[4];
  float4 pw[NW4];

  auto issue = [&](int i) {
    const int tI = i / KT, k0 = (i % KT) * BK;
    const size_t xb = (size_t)(tI * Bsz + b) * Cin * N
                    + (size_t)(k0 + xRow) * N + nBase + xOff;
    if constexpr (XMODE == 0) {
      const float* xp = (const float*)X1v + xb;
      #pragma unroll
      for (int f = 0; f < NXC; ++f) px[f] = *(const float4*)(xp + 4 * f);
    } else {
      const u8* xp = (const u8*)X1v + xb;
      #pragma unroll
      for (int f = 0; f < NXC; ++f) pxu[f] = *(const uint4*)(xp + 16 * f);
    }
    if constexpr (HASX2) {
      uint4 u = *(const uint4*)(X2 + xb);
      pau[0] = u.x; pau[1] = u.y; pau[2] = u.z; pau[3] = u.w;
    }
    const size_t wb = (size_t)(oBase + wO) * Cin + k0 + wK;
    #pragma unroll
    for (int f = 0; f < NW4; ++f) pw[f] = *(const float4*)(Wt + wb + 4 * f);
  };

  auto commit = [&](int bf) {
    if constexpr (XMODE == 0) {
      #pragma unroll
      for (int f = 0; f < NXC; ++f) {
        float4 v = px[f];
        if constexpr (HASX2) {
          u32 a2 = pau[f];
          v.x = v.x + (float)(a2 & 0xffu);
          v.y = v.y + (float)((a2 >> 8) & 0xffu);
          v.z = v.z + (float)((a2 >> 16) & 0xffu);
          v.w = v.w + (float)((a2 >> 24) & 0xffu);
        }
        *(float4*)&XF[((size_t)(bf * BK + xRow)) * XROWF + xOff + 4 * f] = v;
      }
    } else {
      #pragma unroll
      for (int f = 0; f < NXC; ++f)
        *(uint4*)&X8[(size_t)(bf * BK + xRow) * BN + xOff + 16 * f] = pxu[f];
    }
    #pragma unroll
    for (int f = 0; f < NW4; ++f) {
      Ws[bf][wK + 4 * f + 0][wO] = pw[f].x;
      Ws[bf][wK + 4 * f + 1][wO] = pw[f].y;
      Ws[bf][wK + 4 * f + 2][wO] = pw[f].z;
      Ws[bf][wK + 4 * f + 3][wO] = pw[f].w;
    }
  };

  issue(0);
  commit(0);
  __syncthreads();

  for (int tt = 0; tt < TT; ++tt) {
    const int buf = tt & 1;
    if (tt + 1 < TT) issue(tt + 1);

    #pragma unroll
    for (int kk = 0; kk < BK; ++kk) {   // ascending k, bit-exact FMA chain
      float xa[8];
      if constexpr (XMODE == 0) {
        float4 x0 = *(const float4*)&XF[(size_t)(buf * BK + kk) * XROWF + tx * 4];
        float4 x1 = *(const float4*)&XF[(size_t)(buf * BK + kk) * XROWF + 64 + tx * 4];
        xa[0] = x0.x; xa[1] = x0.y; xa[2] = x0.z; xa[3] = x0.w;
        xa[4] = x1.x; xa[5] = x1.y; xa[6] = x1.z; xa[7] = x1.w;
      } else {
        uint2 u = *(const uint2*)&X8[(size_t)(buf * BK + kk) * BN + tx * 8];
        #pragma unroll
        for (int j = 0; j < 4; ++j) xa[j]     = (float)((u.x >> (8 * j)) & 0xffu);
        #pragma unroll
        for (int j = 0; j < 4; ++j) xa[4 + j] = (float)((u.y >> (8 * j)) & 0xffu);
      }
      float wa[P];
      if constexpr (P == 2) {
        float2 w0 = *(const float2*)&Ws[buf][kk][ty * 2];
        wa[0] = w0.x; wa[1] = w0.y;
      } else {
        float4 w0 = *(const float4*)&Ws[buf][kk][ty * P];
        wa[0] = w0.x; wa[1] = w0.y; wa[2] = w0.z; wa[3] = w0.w;
        if constexpr (P == 8) {
          float4 w1 = *(const float4*)&Ws[buf][kk][ty * P + 4];
          wa[4] = w1.x; wa[5] = w1.y; wa[6] = w1.z; wa[7] = w1.w;
        }
      }
      #pragma unroll
      for (int p = 0; p < P; ++p)
        #pragma unroll
        for (int q = 0; q < 8; ++q)
          acc[p][q] = fmaf(wa[p], xa[q], acc[p][q]);
    }

    if ((tt % KT) == KT - 1) {
      const int t = tt / KT;
      const size_t sbase = (size_t)(t * Bsz + b) * Cout * N;
      #pragma unroll
      for (int p = 0; p < P; ++p) {
        const int o = oBase + ty * P + p;
        float4 bv = *(const float4*)&BnL[ty * P + p][0];
        bool spk[8];
        #pragma unroll
        for (int q = 0; q < 8; ++q) {
          float y = acc[p][q];
          if (bias) y = y + bv.w;
          float t1 = y - bv.y;
          float t2 = t1 * bv.x;
          y = t2 + bv.z;
          float m2 = mem[p][q];
          float dd = y - m2;
          m2 = m2 + dd * 0.5f;
          bool sp = (m2 - 0.5f) > 0.0f;
          mem[p][q] = sp ? 0.0f : m2;
          spk[q] = sp;
          acc[p][q] = 0.0f;
        }
        if constexpr (XMODE == 0) {
          const size_t rb0 = sbase + (size_t)o * N + nBase + tx * 4;
          u32 pk0 = 0, pk1 = 0;
          #pragma unroll
          for (int j = 0; j < 4; ++j) {
            if (spk[j])     pk0 |= (1u << (8 * j));
            if (spk[4 + j]) pk1 |= (1u << (8 * j));
          }
          *(u32*)&Sout[rb0]      = pk0;
          *(u32*)&Sout[rb0 + 64] = pk1;
        } else {
          const size_t rb = sbase + (size_t)o * N + nBase + tx * 8;
          if constexpr (OMODE == 0) {
            u32 pk0 = 0, pk1 = 0;
            #pragma unroll
            for (int j = 0; j < 4; ++j) {
              if (spk[j])     pk0 |= (1u << (8 * j));
              if (spk[4 + j]) pk1 |= (1u << (8 * j));
            }
            *(uint2*)&Sout[rb] = make_uint2(pk0, pk1);
          } else {
            float4 xr0 = *(const float4*)&Xres[rb];
            float4 xr1 = *(const float4*)&Xres[rb + 4];
            uint2 av = *(const uint2*)&AOres[rb];
            float xa4[8] = {xr0.x, xr0.y, xr0.z, xr0.w,
                            xr1.x, xr1.y, xr1.z, xr1.w};
            float o4[8];
            #pragma unroll
            for (int j = 0; j < 4; ++j) {
              float sv = spk[j] ? 1.0f : 0.0f;
              float xn = xa4[j] + (float)((av.x >> (8 * j)) & 0xffu);
              o4[j] = xn + sv;
            }
            #pragma unroll
            for (int j = 0; j < 4; ++j) {
              float sv = spk[4 + j] ? 1.0f : 0.0f;
              float xn = xa4[4 + j] + (float)((av.y >> (8 * j)) & 0xffu);
              o4[4 + j] = xn + sv;
            }
            *(float4*)&Fout[rb]     = make_float4(o4[0], o4[1], o4[2], o4[3]);
            *(float4*)&Fout[rb + 4] = make_float4(o4[4], o4[5], o4[6], o4[7]);
          }
        }
      }
    }

    if (tt + 1 < TT) commit((tt + 1) & 1);
    __syncthreads();
  }
}

// ---------------------------------------------------------------------------
// SPLIT kernel 1: conv+BN only, t-PARALLEL (blockIdx.z = t*Bsz + b), f32 y.
// P CAPPED AT 4 (P=8 spilled to 256 VGPR + 2 GB scratch in R9).
// ---------------------------------------------------------------------------
template <int P, int BK, int XMODE, bool HASX2>
__global__ __launch_bounds__(256) void conv_bn_t(
    const void* __restrict__ X1v, const u8* __restrict__ X2,
    const float* __restrict__ Wt, const float* __restrict__ bias,
    const float* __restrict__ bnp, float* __restrict__ Yout,
    int Bsz, int Cin, int Cout, int N)
{
  static_assert(P <= 4, "P=8 spills (R9: 256 VGPR, 2GB scratch)");
  constexpr int BO   = 16 * P;
  constexpr int BN   = 128;
  constexpr int TPRX = 256 / BK;
  constexpr int XPT  = BN / TPRX;
  constexpr int NXC  = (XMODE == 0) ? XPT / 4 : XPT / 16;
  static_assert(XMODE == 1 || (BK == 32 && NXC == 4), "f32 X needs BK=32");
  constexpr int WPT  = BO * BK / 256;
  constexpr int NW4  = WPT / 4;
  constexpr int TPW  = BK / WPT;
  constexpr int WPAD = (P == 4) ? 4 : 2;
  constexpr int WROW = BO + WPAD;
  constexpr int XROWF = BN + 8;

  const int tid = threadIdx.x;
  const int tx = tid & 15, ty = tid >> 4;
  const int nBase = blockIdx.x * BN;
  const int oBase = blockIdx.y * BO;
  const int zb = blockIdx.z;
  const int tI = zb / Bsz, b = zb % Bsz;

  const int KT = Cin / BK;

  __shared__ __align__(16) float Ws[2][BK][WROW];
  __shared__ __align__(16) u8 Xraw[(XMODE == 0) ? (2 * BK * XROWF * 4)
                                                : (2 * BK * BN)];
  __shared__ __align__(16) float BnL[BO][4];

  float* XF = (float*)Xraw;
  u8*    X8 = Xraw;

  if (tid < BO) {
    int o = oBase + tid;
    float g  = bnp[0 * Cout + o];
    float be = bnp[1 * Cout + o];
    float m  = bnp[2 * Cout + o];
    float vv = bnp[3 * Cout + o];
    float d_f = (float)((double)vv + (double)1e-5f);
    float s_f = (float)sqrt((double)d_f);
    BnL[tid][0] = (float)((double)g / (double)s_f);
    BnL[tid][1] = m;
    BnL[tid][2] = be;
    BnL[tid][3] = bias ? bias[o] : 0.0f;
  }

  float acc[P][8];
  #pragma unroll
  for (int p = 0; p < P; ++p)
    #pragma unroll
    for (int q = 0; q < 8; ++q) acc[p][q] = 0.0f;

  const int xRow = tid / TPRX;
  const int xOff = (tid % TPRX) * XPT;
  const int wO   = tid / TPW;
  const int wK   = (tid % TPW) * WPT;

  float4 px[(XMODE == 0) ? NXC : 1];
  uint4  pxu[(XMODE == 1) ? NXC : 1];
  u32    pau[4];
  float4 pw[NW4];

  auto issue = [&](int i) {
    const int k0 = i * BK;
    const size_t xb = (size_t)(tI * Bsz + b) * Cin * N
                    + (size_t)(k0 + xRow) * N + nBase + xOff;
    if constexpr (XMODE == 0) {
      const float* xp = (const float*)X1v + xb;
      #pragma unroll
      for (int f = 0; f < NXC; ++f) px[f] = *(const float4*)(xp + 4 * f);
    } else {
      const u8* xp = (const u8*)X1v + xb;
      #pragma unroll
      for (int f = 0; f < NXC; ++f) pxu[f] = *(const uint4*)(xp + 16 * f);
    }
    if constexpr (HASX2) {
      uint4 u = *(const uint4*)(X2 + xb);
      pau[0] = u.x; pau[1] = u.y; pau[2] = u.z; pau[3] = u.w;
    }
    const size_t wb = (size_t)(oBase + wO) * Cin + k0 + wK;
    #pragma unroll
    for (int f = 0; f < NW4; ++f) pw[f] = *(const float4*)(Wt + wb + 4 * f);
  };

  auto commit = [&](int bf) {
    if constexpr (XMODE == 0) {
      #pragma unroll
      for (int f = 0; f < NXC; ++f) {
        float4 v = px[f];
        if constexpr (HASX2) {
          u32 a2 = pau[f];
          v.x = v.x + (float)(a2 & 0xffu);
          v.y = v.y + (float)((a2 >> 8) & 0xffu);
          v.z = v.z + (float)((a2 >> 16) & 0xffu);
          v.w = v.w + (float)((a2 >> 24) & 0xffu);
        }
        *(float4*)&XF[((size_t)(bf * BK + xRow)) * XROWF + xOff + 4 * f] = v;
      }
    } else {
      #pragma unroll
      for (int f = 0; f < NXC; ++f)
        *(uint4*)&X8[(size_t)(bf * BK + xRow) * BN + xOff + 16 * f] = pxu[f];
    }
    #pragma unroll
    for (int f = 0; f < NW4; ++f) {
      Ws[bf][wK + 4 * f + 0][wO] = pw[f].x;
      Ws[bf][wK + 4 * f + 1][wO] = pw[f].y;
      Ws[bf][wK + 4 * f + 2][wO] = pw[f].z;
      Ws[bf][wK + 4 * f + 3][wO] = pw[f].w;
    }
  };

  issue(0);
  commit(0);
  __syncthreads();

  for (int tt = 0; tt < KT; ++tt) {
    const int buf = tt & 1;
    if (tt + 1 < KT) issue(tt + 1);

    #pragma unroll
    for (int kk = 0; kk < BK; ++kk) {   // ascending k, bit-exact FMA chain
      float xa[8];
      if constexpr (XMODE == 0) {
        float4 x0 = *(const float4*)&XF[(size_t)(buf * BK + kk) * XROWF + tx * 4];
        float4 x1 = *(const float4*)&XF[(size_t)(buf * BK + kk) * XROWF + 64 + tx * 4];
        xa[0] = x0.x; xa[1] = x0.y; xa[2] = x0.z; xa[3] = x0.w;
        xa[4] = x1.x; xa[5] = x1.y; xa[6] = x1.z; xa[7] = x1.w;
      } else {
        uint2 u = *(const uint2*)&X8[(size_t)(buf * BK + kk) * BN + tx * 8];
        #pragma unroll
        for (int j = 0; j < 4; ++j) xa[j]     = (float)((u.x >> (8 * j)) & 0xffu);
        #pragma unroll
        for (int j = 0; j < 4; ++j) xa[4 + j] = (float)((u.y >> (8 * j)) & 0xffu);
      }
      float wa[P];
      if constexpr (P == 2) {
        float2 w0 = *(const float2*)&Ws[buf][kk][ty * 2];
        wa[0] = w0.x; wa[1] = w0.y;
      } else {
        float4 w0 = *(const float4*)&Ws[buf][kk][ty * P];
        wa[0] = w0.x; wa[1] = w0.y; wa[2] = w0.z; wa[3] = w0.w;
      }
      #pragma unroll
      for (int p = 0; p < P; ++p)
        #pragma unroll
        for (int q = 0; q < 8; ++q)
          acc[p][q] = fmaf(wa[p], xa[q], acc[p][q]);
    }

    if (tt + 1 < KT) {
      commit((tt + 1) & 1);
      __syncthreads();
    }
  }

  // epilogue: BN (identical exprs), f32 store
  const size_t sbase = (size_t)(tI * Bsz + b) * Cout * N;
  #pragma unroll
  for (int p = 0; p < P; ++p) {
    const int o = oBase + ty * P + p;
    float4 bv = *(const float4*)&BnL[ty * P + p][0];
    float o4[8];
    #pragma unroll
    for (int q = 0; q < 8; ++q) {
      float y = acc[p][q];
      if (bias) y = y + bv.w;
      float t1 = y - bv.y;
      float t2 = t1 * bv.x;
      o4[q] = t2 + bv.z;
    }
    if constexpr (XMODE == 0) {
      const size_t rb0 = sbase + (size_t)o * N + nBase + tx * 4;
      *(float4*)&Yout[rb0]      = make_float4(o4[0], o4[1], o4[2], o4[3]);
      *(float4*)&Yout[rb0 + 64] = make_float4(o4[4], o4[5], o4[6], o4[7]);
    } else {
      const size_t rb = sbase + (size_t)o * N + nBase + tx * 8;
      *(float4*)&Yout[rb]     = make_float4(o4[0], o4[1], o4[2], o4[3]);
      *(float4*)&Yout[rb + 4] = make_float4(o4[4], o4[5], o4[6], o4[7]);
    }
  }
}

// ---------------------------------------------------------------------------
// SPLIT kernel 2: LIF scan over t (memory-bound elementwise), exprs identical
// to the fused epilogue.  FMODE 0: u8 spikes; 1: final (x + ao) + spike.
// ---------------------------------------------------------------------------
template <int FMODE>
__global__ __launch_bounds__(256) void lif_scan(
    const float* __restrict__ Y, u8* __restrict__ S,
    const float* __restrict__ Xres, const u8* __restrict__ AOres,
    float* __restrict__ Fout, int Bsz, int cnShift)
{
  const size_t off = ((size_t)blockIdx.x * 256 + threadIdx.x) * 4;
  const size_t stride = (size_t)Bsz << cnShift;

  float mem[4];
  #pragma unroll
  for (int j = 0; j < 4; ++j) mem[j] = 0.0f;

  for (int t = 0; t < TSTEPS; ++t) {
    const size_t pos = off + (size_t)t * stride;
    float4 yv = *(const float4*)(Y + pos);
    float ya[4] = {yv.x, yv.y, yv.z, yv.w};
    bool spk[4];
    #pragma unroll
    for (int j = 0; j < 4; ++j) {
      float m2 = mem[j];
      float dd = ya[j] - m2;
      m2 = m2 + dd * 0.5f;
      bool sp = (m2 - 0.5f) > 0.0f;
      mem[j] = sp ? 0.0f : m2;
      spk[j] = sp;
    }
    if constexpr (FMODE == 0) {
      u32 pack = 0;
      #pragma unroll
      for (int j = 0; j < 4; ++j)
        if (spk[j]) pack |= (1u << (8 * j));
      *(u32*)&S[pos] = pack;
    } else {
      float4 xr = *(const float4*)(Xres + pos);
      u32 av = *(const u32*)&AOres[pos];
      float xa4[4] = {xr.x, xr.y, xr.z, xr.w};
      float o4[4];
      #pragma unroll
      for (int j = 0; j < 4; ++j) {
        float sv = spk[j] ? 1.0f : 0.0f;
        float xn = xa4[j] + (float)((av >> (8 * j)) & 0xffu);
        o4[j] = xn + sv;
      }
      *(float4*)&Fout[pos] = make_float4(o4[0], o4[1], o4[2], o4[3]);
    }
  }
}

// Attention + attn-LIF, q @ (k^T v): integer-exact (unchanged, verified).
__global__ __launch_bounds__(256) void attn_lif(
    const u8* __restrict__ Qs, const u8* __restrict__ Ks,
    const u8* __restrict__ Vs, u8* __restrict__ Rs,
    int Bsz, int C, int N)
{
  const int tid = threadIdx.x;
  const int h = blockIdx.x & 15;
  const int b = blockIdx.x >> 4;

  __shared__ u8 qs[16][528];
  __shared__ u8 ks[16][528];
  __shared__ u8 vs[16][528];
  __shared__ int Gs[16][17];

  const int eG = tid >> 4;
  const int dG = tid & 15;
  const int dR = tid >> 4;
  const int nR0 = tid & 15;

  float mem[32];
  #pragma unroll
  for (int i = 0; i < 32; ++i) mem[i] = 0.0f;

  for (int t = 0; t < TSTEPS; ++t) {
    __syncthreads();
    const size_t base = ((size_t)(t * Bsz + b) * C + h * 16) * N;
    for (int i = 0; i < 32; ++i) {
      int flat = tid + 256 * i;
      int d = flat >> 9, n = flat & 511;
      size_t g = base + (size_t)d * N + n;
      qs[d][n] = Qs[g];
      ks[d][n] = Ks[g];
      vs[d][n] = Vs[g];
    }
    __syncthreads();

    int gi = 0;
    for (int n = 0; n < 512; ++n)
      gi += (int)ks[eG][n] * (int)vs[dG][n];
    Gs[eG][dG] = gi;
    __syncthreads();

    int Greg[16];
    #pragma unroll
    for (int e = 0; e < 16; ++e) Greg[e] = Gs[e][dR];

    const size_t obase = ((size_t)(t * Bsz + b) * C + h * 16 + dR) * N;
    for (int j = 0; j < 32; ++j) {
      int n = nR0 + 16 * j;
      int ri = 0;
      #pragma unroll
      for (int e = 0; e < 16; ++e)
        ri += qs[e][n] ? Greg[e] : 0;
      float r = (float)ri * 0.0625f;
      float m2 = mem[j];
      float d = r - m2;
      m2 = m2 + d * 0.5f;
      float s = (m2 - 0.5f) > 0.0f ? 1.0f : 0.0f;
      mem[j] = (s > 0.0f) ? 0.0f : m2;
      Rs[obase + n] = (s > 0.0f) ? (u8)1 : (u8)0;
    }
  }
}

extern "C" void kernel_launch(void* const* d_in, const int* in_sizes, int n_in,
                              void* d_out, int out_size, void* d_ws, size_t ws_size,
                              hipStream_t stream)
{
  const float* x     = (const float*)d_in[0];
  const float* q_w   = (const float*)d_in[1];
  const float* q_bn  = (const float*)d_in[2];
  const float* k_w   = (const float*)d_in[3];
  const float* k_bn  = (const float*)d_in[4];
  const float* v_w   = (const float*)d_in[5];
  const float* v_bn  = (const float*)d_in[6];
  const float* p_w   = (const float*)d_in[7];
  const float* p_bn  = (const float*)d_in[8];
  const float* f1_w  = (const float*)d_in[9];
  const float* f1_b  = (const float*)d_in[10];
  const float* f1_bn = (const float*)d_in[11];
  const float* f2_w  = (const float*)d_in[12];
  const float* f2_b  = (const float*)d_in[13];
  const float* f2_bn = (const float*)d_in[14];

  const int T = 4, B = 16, C = 256, N = 512, Hm = 1024;
  const size_t SZ = (size_t)T * B * C * N;   // u8 spike buffer bytes (8.4 MB)

  char* ws = (char*)d_ws;
  u8* q_s  = (u8*)(ws + 0 * SZ);
  u8* k_s  = (u8*)(ws + 1 * SZ);
  u8* v_s  = (u8*)(ws + 2 * SZ);
  u8* r_s  = (u8*)(ws + 3 * SZ);
  u8* ao_s = (u8*)(ws + 4 * SZ);
  u8* h_s  = (u8*)(ws + 0 * SZ);             // h (4*SZ) overlays dead q/k/v/r

  dim3 blk(256);

  // QKV stays fused (already 3 blocks/CU; splitting adds 100MB f32 traffic).
  dim3 gQKV(N / 128, 3 * (C / 64), B);       // (4,12,16)

  const size_t NEED = 21 * SZ;               // 5*SZ u8 + 16*SZ f32 (fc1 y)

  if (ws_size >= NEED) {
    // ------- HYBRID: fused QKV + t-parallel proj/fc1/fc2 + LIF scans -------
    float* yA = (float*)(ws + 5 * SZ);       // 16*SZ bytes f32 scratch
    float* yp = yA;                          // proj y  (SZ floats)
    float* yh = yA;                          // fc1 y   (4*SZ floats)
    float* yo = yA;                          // fc2 y   (SZ floats)

    dim3 gP(N / 128, C / 64, T * B);         // (4, 4,64)=1024, P=4
    dim3 gF1(N / 128, Hm / 64, T * B);       // (4,16,64)=4096, P=4
    dim3 gF2(N / 128, C / 64, T * B);        // (4, 4,64)=1024, P=4
    const int sC = 17;                       // log2(C*N)
    const int sH = 19;                       // log2(Hm*N)
    dim3 gScanC((B << sC) / 1024);           // 2048
    dim3 gScanH((B << sH) / 1024);           // 8192

    conv_bn_lif<4, 32, 0, false, 0, 3><<<gQKV, blk, 0, stream>>>(
        x, nullptr, q_w, k_w, v_w, nullptr, q_bn, k_bn, v_bn,
        q_s, k_s, v_s, nullptr, nullptr, nullptr, B, C, C, N);

    attn_lif<<<dim3(B * 16), blk, 0, stream>>>(q_s, k_s, v_s, r_s, B, C, N);

    conv_bn_t<4, 32, 1, false><<<gP, blk, 0, stream>>>(
        r_s, nullptr, p_w, nullptr, p_bn, yp, B, C, C, N);
    lif_scan<0><<<gScanC, blk, 0, stream>>>(
        yp, ao_s, nullptr, nullptr, nullptr, B, sC);

    conv_bn_t<4, 32, 0, true><<<gF1, blk, 0, stream>>>(
        x, ao_s, f1_w, f1_b, f1_bn, yh, B, C, Hm, N);
    lif_scan<0><<<gScanH, blk, 0, stream>>>(
        yh, h_s, nullptr, nullptr, nullptr, B, sH);

    conv_bn_t<4, 32, 1, false><<<gF2, blk, 0, stream>>>(
        h_s, nullptr, f2_w, f2_b, f2_bn, yo, B, Hm, C, N);
    lif_scan<1><<<gScanC, blk, 0, stream>>>(
        yo, nullptr, x, ao_s, (float*)d_out, B, sC);
  } else {
    // ---------------- FALLBACK: fully fused (R7/R8 best configs) -----------
    dim3 gP2(N / 128, C / 32, B);            // (4, 8,16)
    dim3 gF1(N / 128, Hm / 128, B);          // (4, 8,16)

    conv_bn_lif<4, 32, 0, false, 0, 3><<<gQKV, blk, 0, stream>>>(
        x, nullptr, q_w, k_w, v_w, nullptr, q_bn, k_bn, v_bn,
        q_s, k_s, v_s, nullptr, nullptr, nullptr, B, C, C, N);

    attn_lif<<<dim3(B * 16), blk, 0, stream>>>(q_s, k_s, v_s, r_s, B, C, N);

    conv_bn_lif<2, 64, 1, false, 0, 1><<<gP2, blk, 0, stream>>>(
        r_s, nullptr, p_w, p_w, p_w, nullptr, p_bn, p_bn, p_bn,
        ao_s, ao_s, ao_s, nullptr, nullptr, nullptr, B, C, C, N);
    conv_bn_lif<8, 32, 0, true, 0, 1><<<gF1, blk, 0, stream>>>(
        x, ao_s, f1_w, f1_w, f1_w, f1_b, f1_bn, f1_bn, f1_bn,
        h_s, h_s, h_s, nullptr, nullptr, nullptr, B, C, Hm, N);
    conv_bn_lif<2, 64, 1, false, 1, 1><<<gP2, blk, 0, stream>>>(
        h_s, nullptr, f2_w, f2_w, f2_w, f2_b, f2_bn, f2_bn, f2_bn,
        nullptr, nullptr, nullptr, x, ao_s, (float*)d_out, B, Hm, C, N);
  }
}